// Round 7
// baseline (286.536 us; speedup 1.0000x reference)
//
#include <hip/hip_runtime.h>
#include <hip/hip_bf16.h>
#include <hip/hip_fp16.h>

#define C_DIM 64
#define M_DIM 8
#define O_DIM 64

typedef _Float16 h8 __attribute__((ext_vector_type(8)));
typedef float f32x4 __attribute__((ext_vector_type(4)));

union HH { __half2 h2; unsigned int u; _Float16 f2[2]; };
union U64 { unsigned long long ll; uint2 v2; };

__device__ __forceinline__ unsigned int packh2(float a, float b) {
    HH x;
    x.f2[0] = (_Float16)a;
    x.f2[1] = (_Float16)b;
    return x.u;
}
__device__ __forceinline__ int rfl(int x) { return __builtin_amdgcn_readfirstlane(x); }

// Fused prep: xu=data@var_u -> f16 rows, data->f16, histogram + per-edge rank.
// Blocks 0..15 additionally repack var_w into MFMA B-fragment order.
__global__ __launch_bounds__(256) void prep_kernel(
    const float* __restrict__ data, const float* __restrict__ u,
    const int* __restrict__ esrc, const float* __restrict__ w,
    _Float16* __restrict__ xuh, unsigned short* __restrict__ datah,
    int* __restrict__ counts, int* __restrict__ rank,
    _Float16* __restrict__ bfrag, int V, int E) {
    int b = blockIdx.x, t = threadIdx.x;
    // wb fold: blocks 0..15
    if (b < 16) {
        int tt = b * 256 + t;
        int kt = tt >> 8;
        int rem = tt & 255;
        int nt = rem >> 6;
        int lane = rem & 63;
        int quad = lane >> 4;
        int n = nt * 16 + (lane & 15);
#pragma unroll
        for (int j = 0; j < 8; ++j) {
            int k = kt * 32 + quad * 8 + j;
            bfrag[(size_t)tt * 8 + j] = (_Float16)w[k * 64 + n];
        }
    }
    // xu: 32 vertices per block, 8 threads per vertex
    int v = b * 32 + (t >> 3), m = t & 7;
    if (v < V) {
        const float* dr = data + (size_t)v * C_DIM;
        float s = 0.f;
#pragma unroll
        for (int c = 0; c < C_DIM; ++c) s = fmaf(dr[c], u[c * M_DIM + m], s);
        xuh[(size_t)v * 8 + m] = (_Float16)s;
    }
    // data -> f16: 2048 elements per block
    size_t base = (size_t)b * 2048 + (size_t)t * 8;
    if (base + 7 < (size_t)V * C_DIM) {
        f32x4 x0 = *(const f32x4*)&data[base];
        f32x4 x1 = *(const f32x4*)&data[base + 4];
        uint4 o;
        o.x = packh2(x0[0], x0[1]);
        o.y = packh2(x0[2], x0[3]);
        o.z = packh2(x1[0], x1[1]);
        o.w = packh2(x1[2], x1[3]);
        *(uint4*)&datah[base] = o;
    }
    // histogram + rank; atomic's return IS the CSR rank
    int stride = gridDim.x * 256;
    for (int e = b * 256 + t; e < E; e += stride)
        rank[e] = atomicAdd(&counts[esrc[e]], 1);
}

// Block-level inclusive scan + block sums
__global__ void scan_a(const int* __restrict__ counts, int* __restrict__ incl,
                       int* __restrict__ bsums, int V) {
    __shared__ int s[1024];
    int g = blockIdx.x * 1024 + threadIdx.x;
    int x = (g < V) ? counts[g] : 0;
    s[threadIdx.x] = x;
    __syncthreads();
    for (int off = 1; off < 1024; off <<= 1) {
        int add = (threadIdx.x >= off) ? s[threadIdx.x - off] : 0;
        __syncthreads();
        s[threadIdx.x] += add;
        __syncthreads();
    }
    if (g < V) incl[g] = s[threadIdx.x];
    if (threadIdx.x == 1023) bsums[blockIdx.x] = s[1023];
}

// Finalize exclusive offsets; block-sum prefix computed in-kernel (nb <= 1024)
__global__ void scan_c2(const int* __restrict__ counts, const int* __restrict__ incl,
                        const int* __restrict__ bsums, int* __restrict__ offsets,
                        int V, int nb) {
    __shared__ int sb[1024];
    int tid = threadIdx.x;
    sb[tid] = (tid < nb) ? bsums[tid] : 0;
    __syncthreads();
    int base = 0;
    for (int i = 0; i < blockIdx.x; ++i) base += sb[i];
    int g = blockIdx.x * 1024 + tid;
    if (g < V) offsets[g] = base + incl[g] - counts[g];
}

// Atomic-free CSR placement: NT-scatter {dst, weight} (8 B) into slot.
__global__ __launch_bounds__(256) void place_kernel(
    const int* __restrict__ esrc, const int* __restrict__ edst,
    const float* __restrict__ ew, const int* __restrict__ offsets,
    const int* __restrict__ rank, unsigned long long* __restrict__ recs, int E) {
    int e = blockIdx.x * blockDim.x + threadIdx.x;
    if (e >= E) return;
    int pos = offsets[esrc[e]] + rank[e];
    U64 r;
    r.v2.x = (unsigned int)edst[e];
    r.v2.y = __float_as_uint(ew[e]);
    __builtin_nontemporal_store(r.ll, &recs[pos]);
}

// Fused: per 16-vertex tile, 4 waves x 4 rows.
// Phase A: one edge/lane over the wave's concatenated 4-row CSR range
//   (owner row via prefix compare; owner xsc staged in LDS) -> gates to LDS.
// Phase B: per-row consume; 16-deep gather pipeline (j scalarized -> saddr),
//   gates read lazily from LDS; 4x v_pk_fma_f16. Same-wave: no barriers.
// Epilogue: 16x16x32 f16 MFMA.
#define A_STRIDE 520
__global__ __launch_bounds__(256) void fused_kernel(
    const unsigned short* __restrict__ datah, const unsigned long long* __restrict__ recs,
    const _Float16* __restrict__ xuh, const float* __restrict__ vc,
    const int* __restrict__ counts, const int* __restrict__ offsets,
    const _Float16* __restrict__ bfragG, const float* __restrict__ bias,
    float* __restrict__ out, int V) {
    __shared__ _Float16 At[16 * A_STRIDE];
    __shared__ int ebj[4][64];
    __shared__ uint4 ebq[4][64];
    __shared__ float xscS[4][4][8];
    __shared__ int pS[4][5];
    __shared__ int oS[4][4];
    int wave = rfl(threadIdx.x >> 6);
    int lane = threadIdx.x & 63;
    int v_base = blockIdx.x * 16;
    int v0 = v_base + wave * 4;

    if (lane < 4) {
        int v = v0 + lane;
        int dd = (v < V) ? counts[v] : 0;
        int oo = (v < V) ? offsets[v] : 0;
        oS[wave][lane] = oo;
        pS[wave][lane + 1] = dd;
    }
    if (lane == 0) {
        pS[wave][0] = 0;
        int s = 0;
#pragma unroll
        for (int i = 1; i <= 4; ++i) {
            s += pS[wave][i];
            pS[wave][i] = s;
        }
    }
    if (lane < 32) {
        int i = lane >> 3, m = lane & 7;
        int v = v0 + i;
        float s = 0.f;
        if (v < V) s = (float)xuh[(size_t)v0 * 8 + lane] + vc[m];
        xscS[wave][i][m] = s;
    }

    HH z; z.u = 0;
    __half2 acc[4][4];
#pragma unroll
    for (int i = 0; i < 4; ++i)
#pragma unroll
        for (int k = 0; k < 4; ++k) acc[i][k] = z.h2;

    int total = rfl(pS[wave][4]);

    for (int c0 = 0; c0 < total; c0 += 64) {
        // ---- Phase A: one edge per lane across the wave's 4 rows ----
        int g = c0 + lane;
        if (g < total) {
            int p1 = pS[wave][1], p2 = pS[wave][2], p3 = pS[wave][3];
            int r = (g >= p1) + (g >= p2) + (g >= p3);
            int pr = (r > 0) ? ((r > 1) ? ((r > 2) ? p3 : p2) : p1) : 0;
            int ob = oS[wave][r];
            int pos = ob + (g - pr);
            U64 rec;
            rec.ll = __builtin_nontemporal_load(&recs[pos]);
            int j = (int)rec.v2.x;
            float w = __uint_as_float(rec.v2.y);
            f32x4 xa = *(const f32x4*)&xscS[wave][r][0];
            f32x4 xb = *(const f32x4*)&xscS[wave][r][4];
            uint4 xr = *(const uint4*)&xuh[(size_t)j * 8];
            HH a, b, c, d;
            a.u = xr.x; b.u = xr.y; c.u = xr.z; d.u = xr.w;
            float lg[8];
            lg[0] = xa[0] - (float)a.f2[0];
            lg[1] = xa[1] - (float)a.f2[1];
            lg[2] = xa[2] - (float)b.f2[0];
            lg[3] = xa[3] - (float)b.f2[1];
            lg[4] = xb[0] - (float)c.f2[0];
            lg[5] = xb[1] - (float)c.f2[1];
            lg[6] = xb[2] - (float)d.f2[0];
            lg[7] = xb[3] - (float)d.f2[1];
            float mx = -1e30f;
#pragma unroll
            for (int m = 0; m < 8; ++m) mx = fmaxf(mx, lg[m]);
            float den = 0.f;
#pragma unroll
            for (int m = 0; m < 8; ++m) {
                lg[m] = __expf(lg[m] - mx);
                den += lg[m];
            }
            float inv = w / den;
#pragma unroll
            for (int m = 0; m < 8; ++m) lg[m] *= inv;
            uint4 qp;
            qp.x = packh2(lg[0], lg[1]);
            qp.y = packh2(lg[2], lg[3]);
            qp.z = packh2(lg[4], lg[5]);
            qp.w = packh2(lg[6], lg[7]);
            ebj[wave][lane] = j;
            ebq[wave][lane] = qp;
        }
        // ---- Phase B: consume this chunk, row by row (same wave) ----
#define CONSUME2(rr, qv, xsv)                                                  \
    do {                                                                       \
        HH q01, q23, q45, q67, xx;                                             \
        q01.u = (qv).x; q23.u = (qv).y;                                        \
        q45.u = (qv).z; q67.u = (qv).w;                                        \
        unsigned int xv_ = (unsigned int)(xsv);                                \
        xx.u = xv_ | (xv_ << 16);                                              \
        acc[rr][0] = __hfma2(xx.h2, q01.h2, acc[rr][0]);                       \
        acc[rr][1] = __hfma2(xx.h2, q23.h2, acc[rr][1]);                       \
        acc[rr][2] = __hfma2(xx.h2, q45.h2, acc[rr][2]);                       \
        acc[rr][3] = __hfma2(xx.h2, q67.h2, acc[rr][3]);                       \
    } while (0)
#pragma unroll
        for (int r2 = 0; r2 < 4; ++r2) {
            int pr0 = rfl(pS[wave][r2]);
            int pr1 = rfl(pS[wave][r2 + 1]);
            int lo = max(pr0, c0);
            int hi = min(pr1, c0 + 64);
            int n = hi - lo;
            if (n <= 0) continue;
            int tb = lo - c0;
            int t = 0;
            // 16-deep gather pipeline; gates read lazily from LDS
            for (; t + 16 <= n; t += 16) {
                int jj[16];
                unsigned short xs[16];
#pragma unroll
                for (int u = 0; u < 16; ++u) jj[u] = rfl(ebj[wave][tb + t + u]);
#pragma unroll
                for (int u = 0; u < 16; ++u) {
                    const unsigned short* xp = datah + ((size_t)jj[u] << 6);
                    xs[u] = xp[lane];
                }
#pragma unroll
                for (int u = 0; u < 16; ++u) {
                    uint4 qv = ebq[wave][tb + t + u];
                    CONSUME2(r2, qv, xs[u]);
                }
            }
            for (; t + 4 <= n; t += 4) {
                int jj[4];
                unsigned short xs[4];
#pragma unroll
                for (int u = 0; u < 4; ++u) jj[u] = rfl(ebj[wave][tb + t + u]);
#pragma unroll
                for (int u = 0; u < 4; ++u) {
                    const unsigned short* xp = datah + ((size_t)jj[u] << 6);
                    xs[u] = xp[lane];
                }
#pragma unroll
                for (int u = 0; u < 4; ++u) {
                    uint4 qv = ebq[wave][tb + t + u];
                    CONSUME2(r2, qv, xs[u]);
                }
            }
            for (; t < n; ++t) {
                int j0 = rfl(ebj[wave][tb + t]);
                const unsigned short* xp = datah + ((size_t)j0 << 6);
                unsigned short xs0 = xp[lane];
                uint4 qv = ebq[wave][tb + t];
                CONSUME2(r2, qv, xs0);
            }
        }
    }

    // Deposit A-tile rows
#pragma unroll
    for (int i = 0; i < 4; ++i) {
        int row = wave * 4 + i;
        HH a01, a23, a45, a67;
        a01.h2 = acc[i][0]; a23.h2 = acc[i][1];
        a45.h2 = acc[i][2]; a67.h2 = acc[i][3];
        _Float16* Ar = &At[row * A_STRIDE + lane];
        Ar[0 * 64] = a01.f2[0];
        Ar[1 * 64] = a01.f2[1];
        Ar[2 * 64] = a23.f2[0];
        Ar[3 * 64] = a23.f2[1];
        Ar[4 * 64] = a45.f2[0];
        Ar[5 * 64] = a45.f2[1];
        Ar[6 * 64] = a67.f2[0];
        Ar[7 * 64] = a67.f2[1];
    }
    __syncthreads();

    // MFMA epilogue: wave = output column tile
    f32x4 cacc = {0.f, 0.f, 0.f, 0.f};
    int quad = lane >> 4;
    int r16 = lane & 15;
#pragma unroll
    for (int kt = 0; kt < 16; ++kt) {
        h8 a = *(const h8*)&At[r16 * A_STRIDE + kt * 32 + quad * 8];
        h8 b = *(const h8*)&bfragG[((size_t)(kt * 4 + wave) * 64 + lane) * 8];
        cacc = __builtin_amdgcn_mfma_f32_16x16x32_f16(a, b, cacc, 0, 0, 0);
    }
#pragma unroll
    for (int r = 0; r < 4; ++r) {
        int row = quad * 4 + r;
        int v = v_base + row;
        if (v < V) {
            int o = wave * 16 + r16;
            out[(size_t)v * 64 + o] = cacc[r] + bias[o];
        }
    }
}

extern "C" void kernel_launch(void* const* d_in, const int* in_sizes, int n_in,
                              void* d_out, int out_size, void* d_ws, size_t ws_size,
                              hipStream_t stream) {
    const float* data  = (const float*)d_in[0];
    const int*   esrc  = (const int*)d_in[1];
    const int*   edst  = (const int*)d_in[2];
    const float* ew    = (const float*)d_in[3];
    const float* var_u = (const float*)d_in[4];
    const float* var_c = (const float*)d_in[5];
    const float* var_w = (const float*)d_in[6];
    const float* var_b = (const float*)d_in[7];
    float* out = (float*)d_out;

    int V = in_sizes[0] / C_DIM;
    int E = in_sizes[1];

    char* ws = (char*)d_ws;
    size_t off = 0;
    auto alloc = [&](size_t bytes) -> void* {
        void* p = ws + off;
        off = (off + bytes + 255) & ~(size_t)255;
        return p;
    };
    _Float16*  xuh     = (_Float16*)alloc((size_t)V * 8 * 2);
    int*       counts  = (int*)alloc((size_t)V * 4);
    int*       offsets = (int*)alloc((size_t)V * 4);
    int*       incl    = (int*)alloc((size_t)V * 4);
    int*       bsums   = (int*)alloc(4096);
    int*       rank    = (int*)alloc((size_t)E * 4);
    unsigned long long* recs = (unsigned long long*)alloc((size_t)E * 8);
    _Float16*  bfrag   = (_Float16*)alloc((size_t)512 * 64 * 2);
    unsigned short* datah = (unsigned short*)alloc((size_t)V * 64 * 2);

    hipMemsetAsync(counts, 0, (size_t)V * 4, stream);

    int pb = (V + 31) / 32;
    prep_kernel<<<pb, 256, 0, stream>>>(data, var_u, esrc, var_w, xuh, datah,
                                        counts, rank, bfrag, V, E);

    int nb = (V + 1023) / 1024;
    scan_a<<<nb, 1024, 0, stream>>>(counts, incl, bsums, V);
    scan_c2<<<nb, 1024, 0, stream>>>(counts, incl, bsums, offsets, V, nb);

    place_kernel<<<(E + 255) / 256, 256, 0, stream>>>(esrc, edst, ew, offsets, rank,
                                                      recs, E);
    fused_kernel<<<(V + 15) / 16, 256, 0, stream>>>(datah, recs, xuh, var_c,
                                                    counts, offsets, bfrag, var_b, out, V);
}

// Round 9
// 255.893 us; speedup vs baseline: 1.1198x; 1.1198x over previous
//
#include <hip/hip_runtime.h>
#include <hip/hip_bf16.h>
#include <hip/hip_fp16.h>

#define C_DIM 64
#define M_DIM 8
#define O_DIM 64

typedef _Float16 h8 __attribute__((ext_vector_type(8)));
typedef float f32x4 __attribute__((ext_vector_type(4)));

union HH { __half2 h2; unsigned int u; _Float16 f2[2]; };

__device__ __forceinline__ unsigned int packh2(float a, float b) {
    HH x;
    x.f2[0] = (_Float16)a;
    x.f2[1] = (_Float16)b;
    return x.u;
}
__device__ __forceinline__ int rfl(int x) { return __builtin_amdgcn_readfirstlane(x); }

// Fused prep: stage 32 data rows in LDS once; emit datah (f16) + xu (f16) from
// the staged copy; histogram + per-edge rank. Blocks 0..15 also repack var_w.
__global__ __launch_bounds__(256) void prep_kernel(
    const float* __restrict__ data, const float* __restrict__ u,
    const int* __restrict__ esrc, const float* __restrict__ w,
    _Float16* __restrict__ xuh, unsigned short* __restrict__ datah,
    int* __restrict__ counts, int* __restrict__ rank,
    _Float16* __restrict__ bfrag, int V, int E) {
    __shared__ float rowsS[32 * 68];   // stride 68: 16B-aligned rows, no conflicts
    __shared__ float uS[512];
    int b = blockIdx.x, t = threadIdx.x;
    // wb fold: blocks 0..15
    if (b < 16) {
        int tt = b * 256 + t;
        int kt = tt >> 8;
        int rem = tt & 255;
        int nt = rem >> 6;
        int lane = rem & 63;
        int quad = lane >> 4;
        int n = nt * 16 + (lane & 15);
#pragma unroll
        for (int j = 0; j < 8; ++j) {
            int k = kt * 32 + quad * 8 + j;
            bfrag[(size_t)tt * 8 + j] = (_Float16)w[k * 64 + n];
        }
    }
    uS[t] = u[t];
    uS[t + 256] = u[t + 256];
    // stage rows + emit datah: thread covers row=t>>3, cols (t&7)*8..+7
    int row = t >> 3;
    int c0 = (t & 7) * 8;
    int v = b * 32 + row;
    if (v < V) {
        const float* dr = data + (size_t)v * C_DIM + c0;
        f32x4 x0 = *(const f32x4*)dr;
        f32x4 x1 = *(const f32x4*)(dr + 4);
        *(f32x4*)&rowsS[row * 68 + c0] = x0;
        *(f32x4*)&rowsS[row * 68 + c0 + 4] = x1;
        uint4 o;
        o.x = packh2(x0[0], x0[1]);
        o.y = packh2(x0[2], x0[3]);
        o.z = packh2(x1[0], x1[1]);
        o.w = packh2(x1[2], x1[3]);
        *(uint4*)&datah[(size_t)v * C_DIM + c0] = o;
    }
    __syncthreads();
    // xu from LDS: thread (row=t>>3, m=t&7)
    int m = t & 7;
    if (v < V) {
        const float* rr = &rowsS[row * 68];
        float s = 0.f;
#pragma unroll
        for (int c = 0; c < C_DIM; ++c) s = fmaf(rr[c], uS[c * M_DIM + m], s);
        xuh[(size_t)v * 8 + m] = (_Float16)s;
    }
    // histogram + rank; atomic's return IS the CSR rank
    int stride = gridDim.x * 256;
    for (int e = b * 256 + t; e < E; e += stride)
        rank[e] = atomicAdd(&counts[esrc[e]], 1);
}

// Single-pass decoupled-lookback exclusive scan: counts[V] -> offsets[V].
// 1024 vertices/block, ticket-ordered blocks, u64 {state:2|value:32} descriptors.
#define SCAN_VPB 1024
__global__ __launch_bounds__(256) void scan_kernel(
    const int* __restrict__ counts, int* __restrict__ offsets,
    unsigned long long* __restrict__ pairs, int* __restrict__ ticket, int V) {
    __shared__ int sA[256];
    __shared__ int bidS, runS;
    int t = threadIdx.x;
    if (t == 0) bidS = atomicAdd(ticket, 1);
    __syncthreads();
    int bid = bidS;
    int base = bid * SCAN_VPB + t * 4;
    int4 c = {0, 0, 0, 0};
    if (base + 3 < V) c = *(const int4*)&counts[base];
    else {
        if (base < V) c.x = counts[base];
        if (base + 1 < V) c.y = counts[base + 1];
        if (base + 2 < V) c.z = counts[base + 2];
    }
    int s = c.x + c.y + c.z + c.w;
    sA[t] = s;
    __syncthreads();
    for (int off = 1; off < 256; off <<= 1) {
        int add = (t >= off) ? sA[t - off] : 0;
        __syncthreads();
        sA[t] += add;
        __syncthreads();
    }
    int total = sA[255];
    int texcl = sA[t] - s;
    if (t == 0) {
        __hip_atomic_store(&pairs[bid],
                           (1ull << 62) | (unsigned long long)(unsigned)total,
                           __ATOMIC_RELEASE, __HIP_MEMORY_SCOPE_AGENT);
        long long running = 0;
        int p = bid - 1;
        while (p >= 0) {
            unsigned long long v2 = __hip_atomic_load(&pairs[p], __ATOMIC_ACQUIRE,
                                                      __HIP_MEMORY_SCOPE_AGENT);
            unsigned long long st = v2 >> 62;
            if (st == 2ull) { running += (int)(v2 & 0xffffffffull); break; }
            if (st == 1ull) { running += (int)(v2 & 0xffffffffull); --p; }
        }
        __hip_atomic_store(&pairs[bid],
                           (2ull << 62) | (unsigned long long)(unsigned)(running + total),
                           __ATOMIC_RELEASE, __HIP_MEMORY_SCOPE_AGENT);
        runS = (int)running;
    }
    __syncthreads();
    int run = runS + texcl;
    if (base < V) offsets[base] = run;
    if (base + 1 < V) offsets[base + 1] = run + c.x;
    if (base + 2 < V) offsets[base + 2] = run + c.x + c.y;
    if (base + 3 < V) offsets[base + 3] = run + c.x + c.y + c.z;
}

// Atomic-free CSR placement: scatter {dst, weight} (8 B) into slot.
__global__ __launch_bounds__(256) void place_kernel(
    const int* __restrict__ esrc, const int* __restrict__ edst,
    const float* __restrict__ ew, const int* __restrict__ offsets,
    const int* __restrict__ rank, uint2* __restrict__ recs, int E) {
    int e = blockIdx.x * blockDim.x + threadIdx.x;
    if (e >= E) return;
    int pos = offsets[esrc[e]] + rank[e];
    uint2 r;
    r.x = (unsigned int)edst[e];
    r.y = __float_as_uint(ew[e]);
    recs[pos] = r;
}

// Fused: per 16-vertex tile, 4 waves x 4 rows. (R6 structure; 12-deep MLP.)
#define A_STRIDE 520
__global__ __launch_bounds__(256) void fused_kernel(
    const unsigned short* __restrict__ datah, const uint2* __restrict__ recs,
    const _Float16* __restrict__ xuh, const float* __restrict__ vc,
    const int* __restrict__ counts, const int* __restrict__ offsets,
    const _Float16* __restrict__ bfragG, const float* __restrict__ bias,
    float* __restrict__ out, int V) {
    __shared__ _Float16 At[16 * A_STRIDE];
    __shared__ int ebj[4][64];
    __shared__ uint4 ebq[4][64];
    __shared__ float xscS[4][4][8];
    __shared__ int pS[4][5];
    __shared__ int oS[4][4];
    int wave = rfl(threadIdx.x >> 6);
    int lane = threadIdx.x & 63;
    int v_base = blockIdx.x * 16;
    int v0 = v_base + wave * 4;

    if (lane < 4) {
        int v = v0 + lane;
        int dd = (v < V) ? counts[v] : 0;
        int oo = (v < V) ? offsets[v] : 0;
        oS[wave][lane] = oo;
        pS[wave][lane + 1] = dd;
    }
    if (lane == 0) {
        pS[wave][0] = 0;
        int s = 0;
#pragma unroll
        for (int i = 1; i <= 4; ++i) {
            s += pS[wave][i];
            pS[wave][i] = s;
        }
    }
    if (lane < 32) {
        int i = lane >> 3, m = lane & 7;
        int v = v0 + i;
        float s = 0.f;
        if (v < V) s = (float)xuh[(size_t)v0 * 8 + lane] + vc[m];
        xscS[wave][i][m] = s;
    }

    HH z; z.u = 0;
    __half2 acc[4][4];
#pragma unroll
    for (int i = 0; i < 4; ++i)
#pragma unroll
        for (int k = 0; k < 4; ++k) acc[i][k] = z.h2;

    int total = rfl(pS[wave][4]);

    for (int c0 = 0; c0 < total; c0 += 64) {
        // ---- Phase A: one edge per lane across the wave's 4 rows ----
        int g = c0 + lane;
        if (g < total) {
            int p1 = pS[wave][1], p2 = pS[wave][2], p3 = pS[wave][3];
            int r = (g >= p1) + (g >= p2) + (g >= p3);
            int pr = (r > 0) ? ((r > 1) ? ((r > 2) ? p3 : p2) : p1) : 0;
            int ob = oS[wave][r];
            int pos = ob + (g - pr);
            uint2 rec = recs[pos];
            int j = (int)rec.x;
            float w = __uint_as_float(rec.y);
            f32x4 xa = *(const f32x4*)&xscS[wave][r][0];
            f32x4 xb = *(const f32x4*)&xscS[wave][r][4];
            uint4 xr = *(const uint4*)&xuh[(size_t)j * 8];
            HH a2, b2, c2, d2;
            a2.u = xr.x; b2.u = xr.y; c2.u = xr.z; d2.u = xr.w;
            float lg[8];
            lg[0] = xa[0] - (float)a2.f2[0];
            lg[1] = xa[1] - (float)a2.f2[1];
            lg[2] = xa[2] - (float)b2.f2[0];
            lg[3] = xa[3] - (float)b2.f2[1];
            lg[4] = xb[0] - (float)c2.f2[0];
            lg[5] = xb[1] - (float)c2.f2[1];
            lg[6] = xb[2] - (float)d2.f2[0];
            lg[7] = xb[3] - (float)d2.f2[1];
            float mx = -1e30f;
#pragma unroll
            for (int m = 0; m < 8; ++m) mx = fmaxf(mx, lg[m]);
            float den = 0.f;
#pragma unroll
            for (int m = 0; m < 8; ++m) {
                lg[m] = __expf(lg[m] - mx);
                den += lg[m];
            }
            float inv = w / den;
#pragma unroll
            for (int m = 0; m < 8; ++m) lg[m] *= inv;
            uint4 qp;
            qp.x = packh2(lg[0], lg[1]);
            qp.y = packh2(lg[2], lg[3]);
            qp.z = packh2(lg[4], lg[5]);
            qp.w = packh2(lg[6], lg[7]);
            ebj[wave][lane] = j;
            ebq[wave][lane] = qp;
        }
        // ---- Phase B: consume, row by row (same wave) ----
#define CONSUME2(rr, qv, xsv)                                                  \
    do {                                                                       \
        HH q01, q23, q45, q67, xx;                                             \
        q01.u = (qv).x; q23.u = (qv).y;                                        \
        q45.u = (qv).z; q67.u = (qv).w;                                        \
        unsigned int xv_ = (unsigned int)(xsv);                                \
        xx.u = xv_ | (xv_ << 16);                                              \
        acc[rr][0] = __hfma2(xx.h2, q01.h2, acc[rr][0]);                       \
        acc[rr][1] = __hfma2(xx.h2, q23.h2, acc[rr][1]);                       \
        acc[rr][2] = __hfma2(xx.h2, q45.h2, acc[rr][2]);                       \
        acc[rr][3] = __hfma2(xx.h2, q67.h2, acc[rr][3]);                       \
    } while (0)
#pragma unroll
        for (int r2 = 0; r2 < 4; ++r2) {
            int pr0 = rfl(pS[wave][r2]);
            int pr1 = rfl(pS[wave][r2 + 1]);
            int lo2 = max(pr0, c0);
            int hi2 = min(pr1, c0 + 64);
            int n = hi2 - lo2;
            if (n <= 0) continue;
            int tb = lo2 - c0;
            int tt = 0;
            // 12-deep gather pipeline; gates read lazily from LDS
            for (; tt + 12 <= n; tt += 12) {
                int jj[12];
                unsigned short xs[12];
#pragma unroll
                for (int u = 0; u < 12; ++u) jj[u] = rfl(ebj[wave][tb + tt + u]);
#pragma unroll
                for (int u = 0; u < 12; ++u) {
                    const unsigned short* xp = datah + ((size_t)jj[u] << 6);
                    xs[u] = xp[lane];
                }
#pragma unroll
                for (int u = 0; u < 12; ++u) {
                    uint4 qv = ebq[wave][tb + tt + u];
                    CONSUME2(r2, qv, xs[u]);
                }
            }
            for (; tt + 4 <= n; tt += 4) {
                int jj[4];
                unsigned short xs[4];
#pragma unroll
                for (int u = 0; u < 4; ++u) jj[u] = rfl(ebj[wave][tb + tt + u]);
#pragma unroll
                for (int u = 0; u < 4; ++u) {
                    const unsigned short* xp = datah + ((size_t)jj[u] << 6);
                    xs[u] = xp[lane];
                }
#pragma unroll
                for (int u = 0; u < 4; ++u) {
                    uint4 qv = ebq[wave][tb + tt + u];
                    CONSUME2(r2, qv, xs[u]);
                }
            }
            for (; tt < n; ++tt) {
                int j0 = rfl(ebj[wave][tb + tt]);
                uint4 qv = ebq[wave][tb + tt];
                const unsigned short* xp = datah + ((size_t)j0 << 6);
                unsigned short xs0 = xp[lane];
                CONSUME2(r2, qv, xs0);
            }
        }
    }

    // Deposit A-tile rows
#pragma unroll
    for (int i = 0; i < 4; ++i) {
        int row = wave * 4 + i;
        HH a01, a23, a45, a67;
        a01.h2 = acc[i][0]; a23.h2 = acc[i][1];
        a45.h2 = acc[i][2]; a67.h2 = acc[i][3];
        _Float16* Ar = &At[row * A_STRIDE + lane];
        Ar[0 * 64] = a01.f2[0];
        Ar[1 * 64] = a01.f2[1];
        Ar[2 * 64] = a23.f2[0];
        Ar[3 * 64] = a23.f2[1];
        Ar[4 * 64] = a45.f2[0];
        Ar[5 * 64] = a45.f2[1];
        Ar[6 * 64] = a67.f2[0];
        Ar[7 * 64] = a67.f2[1];
    }
    __syncthreads();

    // MFMA epilogue: wave = output column tile
    f32x4 cacc = {0.f, 0.f, 0.f, 0.f};
    int quad = lane >> 4;
    int r16 = lane & 15;
#pragma unroll
    for (int kt = 0; kt < 16; ++kt) {
        h8 a = *(const h8*)&At[r16 * A_STRIDE + kt * 32 + quad * 8];
        h8 b = *(const h8*)&bfragG[((size_t)(kt * 4 + wave) * 64 + lane) * 8];
        cacc = __builtin_amdgcn_mfma_f32_16x16x32_f16(a, b, cacc, 0, 0, 0);
    }
#pragma unroll
    for (int r = 0; r < 4; ++r) {
        int row = quad * 4 + r;
        int v = v_base + row;
        if (v < V) {
            int o = wave * 16 + r16;
            out[(size_t)v * 64 + o] = cacc[r] + bias[o];
        }
    }
}

extern "C" void kernel_launch(void* const* d_in, const int* in_sizes, int n_in,
                              void* d_out, int out_size, void* d_ws, size_t ws_size,
                              hipStream_t stream) {
    const float* data  = (const float*)d_in[0];
    const int*   esrc  = (const int*)d_in[1];
    const int*   edst  = (const int*)d_in[2];
    const float* ew    = (const float*)d_in[3];
    const float* var_u = (const float*)d_in[4];
    const float* var_c = (const float*)d_in[5];
    const float* var_w = (const float*)d_in[6];
    const float* var_b = (const float*)d_in[7];
    float* out = (float*)d_out;

    int V = in_sizes[0] / C_DIM;
    int E = in_sizes[1];

    char* ws = (char*)d_ws;
    size_t off = 0;
    auto alloc = [&](size_t bytes) -> void* {
        void* p = ws + off;
        off = (off + bytes + 255) & ~(size_t)255;
        return p;
    };
    // zero region: counts | ticket | pairs (single memset)
    size_t zbytes = (size_t)V * 4 + 256 + 1024;
    char* zr = (char*)alloc(zbytes);
    int* counts = (int*)zr;
    int* ticket = (int*)(zr + (size_t)V * 4);
    unsigned long long* pairs = (unsigned long long*)(zr + (size_t)V * 4 + 256);

    _Float16*  xuh     = (_Float16*)alloc((size_t)V * 8 * 2);
    int*       offsets = (int*)alloc((size_t)V * 4);
    int*       rank    = (int*)alloc((size_t)E * 4);
    uint2*     recs    = (uint2*)alloc((size_t)E * 8);
    _Float16*  bfrag   = (_Float16*)alloc((size_t)512 * 64 * 2);
    unsigned short* datah = (unsigned short*)alloc((size_t)V * 64 * 2);

    hipMemsetAsync(zr, 0, zbytes, stream);

    int pb = (V + 31) / 32;
    prep_kernel<<<pb, 256, 0, stream>>>(data, var_u, esrc, var_w, xuh, datah,
                                        counts, rank, bfrag, V, E);

    int nb = (V + SCAN_VPB - 1) / SCAN_VPB;
    scan_kernel<<<nb, 256, 0, stream>>>(counts, offsets, pairs, ticket, V);

    place_kernel<<<(E + 255) / 256, 256, 0, stream>>>(esrc, edst, ew, offsets, rank,
                                                      recs, E);
    fused_kernel<<<(V + 15) / 16, 256, 0, stream>>>(datah, recs, xuh, var_c,
                                                    counts, offsets, bfrag, var_b, out, V);
}

// Round 10
// 230.259 us; speedup vs baseline: 1.2444x; 1.1113x over previous
//
#include <hip/hip_runtime.h>
#include <hip/hip_bf16.h>
#include <hip/hip_fp16.h>

#define C_DIM 64
#define M_DIM 8
#define O_DIM 64
#define KSLOT 48
#define OVF_CAP 65536

typedef _Float16 h8 __attribute__((ext_vector_type(8)));
typedef float f32x4 __attribute__((ext_vector_type(4)));

union HH { __half2 h2; unsigned int u; _Float16 f2[2]; };

__device__ __forceinline__ unsigned int packh2(float a, float b) {
    HH x;
    x.f2[0] = (_Float16)a;
    x.f2[1] = (_Float16)b;
    return x.u;
}
__device__ __forceinline__ int rfl(int x) { return __builtin_amdgcn_readfirstlane(x); }

// Fused prep: xu=data@var_u -> f16 rows, data->f16, and histogram+direct
// padded-CSR placement (slot = src*KSLOT + rank from the ONE atomic per edge).
// Blocks 0..15 also repack var_w into MFMA B-fragment order.
__global__ __launch_bounds__(256) void prep_kernel(
    const float* __restrict__ data, const float* __restrict__ u,
    const int* __restrict__ esrc, const int* __restrict__ edst,
    const float* __restrict__ ew, const float* __restrict__ w,
    _Float16* __restrict__ xuh, unsigned short* __restrict__ datah,
    int* __restrict__ counts, uint2* __restrict__ recs,
    int* __restrict__ ovf_cnt, int* __restrict__ ovf,
    _Float16* __restrict__ bfrag, int V, int E) {
    int b = blockIdx.x, t = threadIdx.x;
    // wb fold: blocks 0..15
    if (b < 16) {
        int tt = b * 256 + t;
        int kt = tt >> 8;
        int rem = tt & 255;
        int nt = rem >> 6;
        int lane = rem & 63;
        int quad = lane >> 4;
        int n = nt * 16 + (lane & 15);
#pragma unroll
        for (int j = 0; j < 8; ++j) {
            int k = kt * 32 + quad * 8 + j;
            bfrag[(size_t)tt * 8 + j] = (_Float16)w[k * 64 + n];
        }
    }
    // xu: 32 vertices per block, 8 threads per vertex
    int v = b * 32 + (t >> 3), m = t & 7;
    if (v < V) {
        const float* dr = data + (size_t)v * C_DIM;
        float s = 0.f;
#pragma unroll
        for (int c = 0; c < C_DIM; ++c) s = fmaf(dr[c], u[c * M_DIM + m], s);
        xuh[(size_t)v * 8 + m] = (_Float16)s;
    }
    // data -> f16: 2048 elements per block
    size_t base = (size_t)b * 2048 + (size_t)t * 8;
    if (base + 7 < (size_t)V * C_DIM) {
        f32x4 x0 = *(const f32x4*)&data[base];
        f32x4 x1 = *(const f32x4*)&data[base + 4];
        uint4 o;
        o.x = packh2(x0[0], x0[1]);
        o.y = packh2(x0[2], x0[3]);
        o.z = packh2(x1[0], x1[1]);
        o.w = packh2(x1[2], x1[3]);
        *(uint4*)&datah[base] = o;
    }
    // histogram + direct padded-CSR placement (single trip: grid covers E)
    int e = b * 256 + t;
    if (e < E) {
        int s = esrc[e];
        int rank = atomicAdd(&counts[s], 1);
        if (rank < KSLOT) {
            uint2 r;
            r.x = (unsigned int)edst[e];
            r.y = __float_as_uint(ew[e]);
            recs[(size_t)s * KSLOT + rank] = r;
        } else {
            int oi = atomicAdd(ovf_cnt, 1);
            if (oi < OVF_CAP) ovf[oi] = e;
        }
    }
}

// Fused: per 16-vertex tile, 4 waves x 4 rows (R6 structure, padded CSR).
#define A_STRIDE 520
__global__ __launch_bounds__(256) void fused_kernel(
    const unsigned short* __restrict__ datah, const uint2* __restrict__ recs,
    const _Float16* __restrict__ xuh, const float* __restrict__ vc,
    const int* __restrict__ counts, const _Float16* __restrict__ bfragG,
    const float* __restrict__ bias, float* __restrict__ out, int V) {
    __shared__ _Float16 At[16 * A_STRIDE];
    __shared__ int ebj[4][64];
    __shared__ uint4 ebq[4][64];
    __shared__ float xscS[4][4][8];
    __shared__ int pS[4][5];
    __shared__ int oS[4][4];
    int wave = rfl(threadIdx.x >> 6);
    int lane = threadIdx.x & 63;
    int v_base = blockIdx.x * 16;
    int v0 = v_base + wave * 4;

    if (lane < 4) {
        int v = v0 + lane;
        int dd = (v < V) ? min(counts[v], KSLOT) : 0;
        oS[wave][lane] = v * KSLOT;
        pS[wave][lane + 1] = dd;
    }
    if (lane == 0) {
        pS[wave][0] = 0;
        int s = 0;
#pragma unroll
        for (int i = 1; i <= 4; ++i) {
            s += pS[wave][i];
            pS[wave][i] = s;
        }
    }
    if (lane < 32) {
        int i = lane >> 3, m = lane & 7;
        int v = v0 + i;
        float s = 0.f;
        if (v < V) s = (float)xuh[(size_t)v0 * 8 + lane] + vc[m];
        xscS[wave][i][m] = s;
    }

    HH z; z.u = 0;
    __half2 acc[4][4];
#pragma unroll
    for (int i = 0; i < 4; ++i)
#pragma unroll
        for (int k = 0; k < 4; ++k) acc[i][k] = z.h2;

    int total = rfl(pS[wave][4]);

    for (int c0 = 0; c0 < total; c0 += 64) {
        // ---- Phase A: one edge per lane across the wave's 4 rows ----
        int g = c0 + lane;
        if (g < total) {
            int p1 = pS[wave][1], p2 = pS[wave][2], p3 = pS[wave][3];
            int r = (g >= p1) + (g >= p2) + (g >= p3);
            int pr = (r > 0) ? ((r > 1) ? ((r > 2) ? p3 : p2) : p1) : 0;
            int ob = oS[wave][r];
            int pos = ob + (g - pr);
            uint2 rec = recs[pos];
            int j = (int)rec.x;
            float w = __uint_as_float(rec.y);
            f32x4 xa = *(const f32x4*)&xscS[wave][r][0];
            f32x4 xb = *(const f32x4*)&xscS[wave][r][4];
            uint4 xr = *(const uint4*)&xuh[(size_t)j * 8];
            HH a2, b2, c2, d2;
            a2.u = xr.x; b2.u = xr.y; c2.u = xr.z; d2.u = xr.w;
            float lg[8];
            lg[0] = xa[0] - (float)a2.f2[0];
            lg[1] = xa[1] - (float)a2.f2[1];
            lg[2] = xa[2] - (float)b2.f2[0];
            lg[3] = xa[3] - (float)b2.f2[1];
            lg[4] = xb[0] - (float)c2.f2[0];
            lg[5] = xb[1] - (float)c2.f2[1];
            lg[6] = xb[2] - (float)d2.f2[0];
            lg[7] = xb[3] - (float)d2.f2[1];
            float mx = -1e30f;
#pragma unroll
            for (int m = 0; m < 8; ++m) mx = fmaxf(mx, lg[m]);
            float den = 0.f;
#pragma unroll
            for (int m = 0; m < 8; ++m) {
                lg[m] = __expf(lg[m] - mx);
                den += lg[m];
            }
            float inv = w / den;
#pragma unroll
            for (int m = 0; m < 8; ++m) lg[m] *= inv;
            uint4 qp;
            qp.x = packh2(lg[0], lg[1]);
            qp.y = packh2(lg[2], lg[3]);
            qp.z = packh2(lg[4], lg[5]);
            qp.w = packh2(lg[6], lg[7]);
            ebj[wave][lane] = j;
            ebq[wave][lane] = qp;
        }
        // ---- Phase B: consume, row by row (same wave, 8-deep MLP) ----
#define CONSUME2(rr, qv, xsv)                                                  \
    do {                                                                       \
        HH q01, q23, q45, q67, xx;                                             \
        q01.u = (qv).x; q23.u = (qv).y;                                        \
        q45.u = (qv).z; q67.u = (qv).w;                                        \
        unsigned int xv_ = (unsigned int)(xsv);                                \
        xx.u = xv_ | (xv_ << 16);                                              \
        acc[rr][0] = __hfma2(xx.h2, q01.h2, acc[rr][0]);                       \
        acc[rr][1] = __hfma2(xx.h2, q23.h2, acc[rr][1]);                       \
        acc[rr][2] = __hfma2(xx.h2, q45.h2, acc[rr][2]);                       \
        acc[rr][3] = __hfma2(xx.h2, q67.h2, acc[rr][3]);                       \
    } while (0)
#pragma unroll
        for (int r2 = 0; r2 < 4; ++r2) {
            int pr0 = rfl(pS[wave][r2]);
            int pr1 = rfl(pS[wave][r2 + 1]);
            int lo2 = max(pr0, c0);
            int hi2 = min(pr1, c0 + 64);
            int n = hi2 - lo2;
            if (n <= 0) continue;
            int tb = lo2 - c0;
            int tt = 0;
            for (; tt + 8 <= n; tt += 8) {
                int jj[8];
                uint4 qq[8];
                unsigned short xs[8];
#pragma unroll
                for (int u = 0; u < 8; ++u) {
                    jj[u] = rfl(ebj[wave][tb + tt + u]);
                    qq[u] = ebq[wave][tb + tt + u];
                }
#pragma unroll
                for (int u = 0; u < 8; ++u) {
                    const unsigned short* xp = datah + ((size_t)jj[u] << 6);
                    xs[u] = xp[lane];
                }
#pragma unroll
                for (int u = 0; u < 8; ++u) CONSUME2(r2, qq[u], xs[u]);
            }
            for (; tt + 4 <= n; tt += 4) {
                int jj[4];
                uint4 qq[4];
                unsigned short xs[4];
#pragma unroll
                for (int u = 0; u < 4; ++u) {
                    jj[u] = rfl(ebj[wave][tb + tt + u]);
                    qq[u] = ebq[wave][tb + tt + u];
                }
#pragma unroll
                for (int u = 0; u < 4; ++u) {
                    const unsigned short* xp = datah + ((size_t)jj[u] << 6);
                    xs[u] = xp[lane];
                }
#pragma unroll
                for (int u = 0; u < 4; ++u) CONSUME2(r2, qq[u], xs[u]);
            }
            for (; tt < n; ++tt) {
                int j0 = rfl(ebj[wave][tb + tt]);
                uint4 qv = ebq[wave][tb + tt];
                const unsigned short* xp = datah + ((size_t)j0 << 6);
                unsigned short xs0 = xp[lane];
                CONSUME2(r2, qv, xs0);
            }
        }
    }

    // Deposit A-tile rows
#pragma unroll
    for (int i = 0; i < 4; ++i) {
        int row = wave * 4 + i;
        HH a01, a23, a45, a67;
        a01.h2 = acc[i][0]; a23.h2 = acc[i][1];
        a45.h2 = acc[i][2]; a67.h2 = acc[i][3];
        _Float16* Ar = &At[row * A_STRIDE + lane];
        Ar[0 * 64] = a01.f2[0];
        Ar[1 * 64] = a01.f2[1];
        Ar[2 * 64] = a23.f2[0];
        Ar[3 * 64] = a23.f2[1];
        Ar[4 * 64] = a45.f2[0];
        Ar[5 * 64] = a45.f2[1];
        Ar[6 * 64] = a67.f2[0];
        Ar[7 * 64] = a67.f2[1];
    }
    __syncthreads();

    // MFMA epilogue: wave = output column tile
    f32x4 cacc = {0.f, 0.f, 0.f, 0.f};
    int quad = lane >> 4;
    int r16 = lane & 15;
#pragma unroll
    for (int kt = 0; kt < 16; ++kt) {
        h8 a = *(const h8*)&At[r16 * A_STRIDE + kt * 32 + quad * 8];
        h8 b = *(const h8*)&bfragG[((size_t)(kt * 4 + wave) * 64 + lane) * 8];
        cacc = __builtin_amdgcn_mfma_f32_16x16x32_f16(a, b, cacc, 0, 0, 0);
    }
#pragma unroll
    for (int r = 0; r < 4; ++r) {
        int row = quad * 4 + r;
        int v = v_base + row;
        if (v < V) {
            int o = wave * 16 + r16;
            out[(size_t)v * 64 + o] = cacc[r] + bias[o];
        }
    }
}

// Exact handling of overflow edges (rank >= KSLOT): one wave per edge,
// lane = output channel; f32 math; atomicAdd into out. No-op when empty.
__global__ __launch_bounds__(256) void cleanup_kernel(
    const int* __restrict__ ovf_cnt, const int* __restrict__ ovf,
    const int* __restrict__ esrc, const int* __restrict__ edst,
    const float* __restrict__ ew, const _Float16* __restrict__ xuh,
    const float* __restrict__ vc, const float* __restrict__ var_w,
    const unsigned short* __restrict__ datah, float* __restrict__ out) {
    int n = min(*ovf_cnt, OVF_CAP);
    int nw = gridDim.x * (blockDim.x >> 6);
    int wid = blockIdx.x * (blockDim.x >> 6) + (threadIdx.x >> 6);
    int lane = threadIdx.x & 63;
    for (int i = wid; i < n; i += nw) {
        int e = ovf[i];
        int s = esrc[e], j = edst[e];
        float w = ew[e];
        float lg[8];
        float mx = -1e30f;
#pragma unroll
        for (int m = 0; m < 8; ++m) {
            lg[m] = (float)xuh[(size_t)s * 8 + m] - (float)xuh[(size_t)j * 8 + m] + vc[m];
            mx = fmaxf(mx, lg[m]);
        }
        float den = 0.f;
#pragma unroll
        for (int m = 0; m < 8; ++m) {
            lg[m] = __expf(lg[m] - mx);
            den += lg[m];
        }
        float inv = w / den;
        float t = 0.f;
#pragma unroll
        for (int m = 0; m < 8; ++m) {
            float sum = 0.f;
            for (int c = 0; c < C_DIM; ++c) {
                HH x;
                x.u = (unsigned int)datah[(size_t)j * 64 + c];
                sum = fmaf((float)x.f2[0], var_w[((size_t)m * 64 + c) * 64 + lane], sum);
            }
            t = fmaf(lg[m] * inv, sum, t);
        }
        atomicAdd(&out[(size_t)s * 64 + lane], t);
    }
}

extern "C" void kernel_launch(void* const* d_in, const int* in_sizes, int n_in,
                              void* d_out, int out_size, void* d_ws, size_t ws_size,
                              hipStream_t stream) {
    const float* data  = (const float*)d_in[0];
    const int*   esrc  = (const int*)d_in[1];
    const int*   edst  = (const int*)d_in[2];
    const float* ew    = (const float*)d_in[3];
    const float* var_u = (const float*)d_in[4];
    const float* var_c = (const float*)d_in[5];
    const float* var_w = (const float*)d_in[6];
    const float* var_b = (const float*)d_in[7];
    float* out = (float*)d_out;

    int V = in_sizes[0] / C_DIM;
    int E = in_sizes[1];

    char* ws = (char*)d_ws;
    size_t off = 0;
    auto alloc = [&](size_t bytes) -> void* {
        void* p = ws + off;
        off = (off + bytes + 255) & ~(size_t)255;
        return p;
    };
    // zero region: counts | ovf_cnt (single memset)
    size_t zbytes = (size_t)V * 4 + 256;
    char* zr = (char*)alloc(zbytes);
    int* counts  = (int*)zr;
    int* ovf_cnt = (int*)(zr + (size_t)V * 4);

    _Float16*  xuh   = (_Float16*)alloc((size_t)V * 8 * 2);
    int*       ovf   = (int*)alloc((size_t)OVF_CAP * 4);
    uint2*     recs  = (uint2*)alloc((size_t)V * KSLOT * 8);
    _Float16*  bfrag = (_Float16*)alloc((size_t)512 * 64 * 2);
    unsigned short* datah = (unsigned short*)alloc((size_t)V * 64 * 2);

    hipMemsetAsync(zr, 0, zbytes, stream);

    int pb = (E + 255) / 256;   // covers E single-trip; also >= ceil(V/32)
    prep_kernel<<<pb, 256, 0, stream>>>(data, var_u, esrc, edst, ew, var_w,
                                        xuh, datah, counts, recs, ovf_cnt, ovf,
                                        bfrag, V, E);
    fused_kernel<<<(V + 15) / 16, 256, 0, stream>>>(datah, recs, xuh, var_c,
                                                    counts, bfrag, var_b, out, V);
    cleanup_kernel<<<8, 256, 0, stream>>>(ovf_cnt, ovf, esrc, edst, ew, xuh,
                                          var_c, var_w, datah, out);
}